// Round 2
// baseline (121.205 us; speedup 1.0000x reference)
//
#include <hip/hip_runtime.h>

// Spatial transformer, bilinear sampling, NCHW fp32.
// X: (B, C, H, W) = (32, 3, 512, 512), theta: (B, 6), out: (B, C, H, W).

#define ST_H 512
#define ST_W 512
#define ST_C 3
// 4 pixels per thread: float4 stores, 48 outstanding gathers/thread.

typedef float f4 __attribute__((ext_vector_type(4)));

__global__ __launch_bounds__(256) void st_bilinear_kernel(
    const float* __restrict__ X,
    const float* __restrict__ theta,
    float* __restrict__ out,
    int B, int chunk)
{
    // XCD-aware swizzle: 8 XCDs, contiguous chunk of blocks per XCD so each
    // XCD's L2 sees a compact set of images (X per image = 3.1 MB < 4 MB L2).
    int bid = blockIdx.x;
    bid = (bid & 7) * chunk + (bid >> 3);

    const int gid = bid * 256 + threadIdx.x;       // one thread = 4 pixels
    const int pix = (gid << 2) & (ST_H * ST_W - 1);
    const int b   = gid >> 16;                     // 2^16 threads per image
    if (b >= B) return;

    const int h  = pix >> 9;        // row (all 4 px same row: 512 % 4 == 0)
    const int w0 = pix & 511;

    const float* t = theta + b * 6;
    const float t00 = t[0], t01 = t[1], t02 = t[2];
    const float t10 = t[3], t11 = t[4], t12 = t[5];

    // yg constant across the 4 px
    const float yg = (float)(-1.0 + (2.0 / 511.0) * (double)h);
    const float by_x = t01 * yg + t02;   // x_s = t00*xg + (t01*yg + t02)
    const float by_y = t11 * yg + t12;

    float wa[4], wb[4], wc[4], wd[4];
    int ia[4], ib[4], ic[4], id[4];

#pragma unroll
    for (int j = 0; j < 4; ++j) {
        const int w = w0 + j;
        const float xg = (float)(-1.0 + (2.0 / 511.0) * (double)w);
        // match reference op order: t00*xg + t01*yg + t02
        const float x_s = t00 * xg + (t01 * yg + t02);
        const float y_s = t10 * xg + (t11 * yg + t12);
        (void)by_x; (void)by_y;
        const float x = (x_s + 1.0f) * (0.5f * ST_W);
        const float y = (y_s + 1.0f) * (0.5f * ST_H);

        const float fx0 = floorf(x);
        const float fy0 = floorf(y);
        const int x0 = (int)fx0, y0 = (int)fy0;
        const int x1 = x0 + 1,  y1 = y0 + 1;

        const int x0c = min(max(x0, 0), ST_W - 1);
        const int x1c = min(max(x1, 0), ST_W - 1);
        const int y0c = min(max(y0, 0), ST_H - 1);
        const int y1c = min(max(y1, 0), ST_H - 1);

        // weights use CLIPPED coords cast to float (reference semantics)
        const float x0f = (float)x0c, x1f = (float)x1c;
        const float y0f = (float)y0c, y1f = (float)y1c;
        wa[j] = (x1f - x) * (y1f - y);
        wb[j] = (x1f - x) * (y - y0f);
        wc[j] = (x - x0f) * (y1f - y);
        wd[j] = (x - x0f) * (y - y0f);

        ia[j] = y0c * ST_W + x0c;
        ib[j] = y1c * ST_W + x0c;
        ic[j] = y0c * ST_W + x1c;
        id[j] = y1c * ST_W + x1c;
    }

    const float* __restrict__ Xb = X + (size_t)b * (ST_C * ST_H * ST_W);
    float* __restrict__ ob = out + (size_t)b * (ST_C * ST_H * ST_W) + pix;

#pragma unroll
    for (int c = 0; c < ST_C; ++c) {
        const float* __restrict__ Xc = Xb + c * (ST_H * ST_W);
        f4 v;
#pragma unroll
        for (int j = 0; j < 4; ++j) {
            const float Ia = Xc[ia[j]];
            const float Ib = Xc[ib[j]];
            const float Ic = Xc[ic[j]];
            const float Id = Xc[id[j]];
            v[j] = wa[j] * Ia + wb[j] * Ib + wc[j] * Ic + wd[j] * Id;
        }
        // nontemporal: output has zero reuse; keep L2 for the gathers
        __builtin_nontemporal_store(v, (f4*)(ob + c * (ST_H * ST_W)));
    }
}

extern "C" void kernel_launch(void* const* d_in, const int* in_sizes, int n_in,
                              void* d_out, int out_size, void* d_ws, size_t ws_size,
                              hipStream_t stream) {
    const float* X     = (const float*)d_in[0];
    const float* theta = (const float*)d_in[1];
    float* out         = (float*)d_out;

    const int B = in_sizes[1] / 6;                     // 32
    const int total_threads = B * (ST_H * ST_W) / 4;   // 4 px per thread
    const int block = 256;
    const int grid = total_threads / block;            // 8192 (divisible by 8)
    const int chunk = grid / 8;                        // blocks per XCD

    st_bilinear_kernel<<<grid, block, 0, stream>>>(X, theta, out, B, chunk);
}

// Round 3
// 68.370 us; speedup vs baseline: 1.7728x; 1.7728x over previous
//
#include <hip/hip_runtime.h>

// Spatial transformer, bilinear sampling, NCHW fp32.
// X: (B, C, H, W) = (32, 3, 512, 512), theta: (B, 6), out: (B, C, H, W).
//
// R3: round-1 structure (1 px/thread, lane-contiguous gathers, 20 VGPR)
//     + nontemporal stores (write stream bypasses L2/L3 -> X stays cached)
//     + XCD-contiguous block swizzle (adjacent rows' shared input row stays
//       in one XCD's L2).

#define ST_H 512
#define ST_W 512
#define ST_C 3

__global__ __launch_bounds__(256) void st_bilinear_kernel(
    const float* __restrict__ X,
    const float* __restrict__ theta,
    float* __restrict__ out,
    int B, int chunk)
{
    // XCD swizzle: default dispatch round-robins blocks over 8 XCDs;
    // remap so each XCD owns a contiguous range of blocks (grid % 8 == 0).
    int bid = blockIdx.x;
    bid = (bid & 7) * chunk + (bid >> 3);

    const int gid = bid * 256 + threadIdx.x;
    const int pix = gid & (ST_H * ST_W - 1);   // 2^18 pixels per image
    const int b   = gid >> 18;
    if (b >= B) return;

    const int h = pix >> 9;      // / 512
    const int w = pix & 511;

    const float* t = theta + b * 6;
    const float t00 = t[0], t01 = t[1], t02 = t[2];
    const float t10 = t[3], t11 = t[4], t12 = t[5];

    // linspace(-1, 1, 512) computed like np.linspace (f64 then cast)
    const float xg = (float)(-1.0 + (2.0 / 511.0) * (double)w);
    const float yg = (float)(-1.0 + (2.0 / 511.0) * (double)h);

    const float x_s = t00 * xg + t01 * yg + t02;
    const float y_s = t10 * xg + t11 * yg + t12;
    const float x = (x_s + 1.0f) * (0.5f * ST_W);
    const float y = (y_s + 1.0f) * (0.5f * ST_H);

    const float fx0 = floorf(x);
    const float fy0 = floorf(y);
    const int x0 = (int)fx0, y0 = (int)fy0;
    const int x1 = x0 + 1,  y1 = y0 + 1;

    const int x0c = min(max(x0, 0), ST_W - 1);
    const int x1c = min(max(x1, 0), ST_W - 1);
    const int y0c = min(max(y0, 0), ST_H - 1);
    const int y1c = min(max(y1, 0), ST_H - 1);

    // weights use CLIPPED coords cast to float (reference semantics)
    const float x0f = (float)x0c, x1f = (float)x1c;
    const float y0f = (float)y0c, y1f = (float)y1c;
    const float wa = (x1f - x) * (y1f - y);
    const float wb = (x1f - x) * (y - y0f);
    const float wc = (x - x0f) * (y1f - y);
    const float wd = (x - x0f) * (y - y0f);

    const int ia = y0c * ST_W + x0c;
    const int ib = y1c * ST_W + x0c;
    const int ic = y0c * ST_W + x1c;
    const int id = y1c * ST_W + x1c;

    const float* __restrict__ Xb = X + (size_t)b * (ST_C * ST_H * ST_W);
    float* __restrict__ ob = out + (size_t)b * (ST_C * ST_H * ST_W) + pix;

#pragma unroll
    for (int c = 0; c < ST_C; ++c) {
        const float* __restrict__ Xc = Xb + c * (ST_H * ST_W);
        const float Ia = Xc[ia];
        const float Ib = Xc[ib];
        const float Ic = Xc[ic];
        const float Id = Xc[id];
        const float v = wa * Ia + wb * Ib + wc * Ic + wd * Id;
        // nontemporal: output has zero reuse; keep L2/L3 for the gathers
        __builtin_nontemporal_store(v, ob + c * (ST_H * ST_W));
    }
}

extern "C" void kernel_launch(void* const* d_in, const int* in_sizes, int n_in,
                              void* d_out, int out_size, void* d_ws, size_t ws_size,
                              hipStream_t stream) {
    const float* X     = (const float*)d_in[0];
    const float* theta = (const float*)d_in[1];
    float* out         = (float*)d_out;

    const int B = in_sizes[1] / 6;                  // 32
    const int total = B * ST_H * ST_W;
    const int block = 256;
    const int grid = (total + block - 1) / block;   // 32768, divisible by 8
    const int chunk = grid / 8;                     // blocks per XCD

    st_bilinear_kernel<<<grid, block, 0, stream>>>(X, theta, out, B, chunk);
}

// Round 4
// 47.446 us; speedup vs baseline: 2.5546x; 1.4410x over previous
//
#include <hip/hip_runtime.h>

// Spatial transformer, bilinear sampling, NCHW fp32.
// X: (B, C, H, W) = (32, 3, 512, 512), theta: (B, 6), out: (B, C, H, W).
//
// R4: x0/x1 corners are adjacent -> one unaligned float2 gather per row
//     fetches both (halves L1 tag lookups, 12 gathers/px -> 6).
//     Border semantics preserved via clamp-to-[0,W-2] + lane select.
//     Keeps: 1 px/thread lane-contiguous mapping, nt stores, XCD swizzle.

#define ST_H 512
#define ST_W 512
#define ST_C 3

typedef float f2 __attribute__((ext_vector_type(2)));
// 8B vector load with only 4B alignment guarantee (gfx950 unaligned VMEM).
struct __attribute__((packed, aligned(4))) f2_a4 { f2 v; };

__global__ __launch_bounds__(256) void st_bilinear_kernel(
    const float* __restrict__ X,
    const float* __restrict__ theta,
    float* __restrict__ out,
    int B, int chunk)
{
    // XCD swizzle: each XCD owns a contiguous range of blocks (grid % 8 == 0).
    int bid = blockIdx.x;
    bid = (bid & 7) * chunk + (bid >> 3);

    const int gid = bid * 256 + threadIdx.x;
    const int pix = gid & (ST_H * ST_W - 1);   // 2^18 pixels per image
    const int b   = gid >> 18;
    if (b >= B) return;

    const int h = pix >> 9;      // / 512
    const int w = pix & 511;

    const float* t = theta + b * 6;
    const float t00 = t[0], t01 = t[1], t02 = t[2];
    const float t10 = t[3], t11 = t[4], t12 = t[5];

    // linspace(-1, 1, 512) computed like np.linspace (f64 then cast)
    const float xg = (float)(-1.0 + (2.0 / 511.0) * (double)w);
    const float yg = (float)(-1.0 + (2.0 / 511.0) * (double)h);

    const float x_s = t00 * xg + t01 * yg + t02;
    const float y_s = t10 * xg + t11 * yg + t12;
    const float x = (x_s + 1.0f) * (0.5f * ST_W);
    const float y = (y_s + 1.0f) * (0.5f * ST_H);

    const int x0 = (int)floorf(x);
    const int y0 = (int)floorf(y);
    const int x1 = x0 + 1, y1 = y0 + 1;

    const int x0c = min(max(x0, 0), ST_W - 1);
    const int x1c = min(max(x1, 0), ST_W - 1);
    const int y0c = min(max(y0, 0), ST_H - 1);
    const int y1c = min(max(y1, 0), ST_H - 1);

    // weights use CLIPPED coords cast to float (reference semantics)
    const float x0f = (float)x0c, x1f = (float)x1c;
    const float y0f = (float)y0c, y1f = (float)y1c;
    const float wa = (x1f - x) * (y1f - y);
    const float wb = (x1f - x) * (y - y0f);
    const float wc = (x - x0f) * (y1f - y);
    const float wd = (x - x0f) * (y - y0f);

    // pair-gather start column; covers {x0c, x1c} for all clamp cases
    const int xa = min(max(x0, 0), ST_W - 2);
    const bool hi = (x0 >= ST_W - 1);   // both corners clamped to W-1 -> take .y
    const bool lo = (x0 < 0);           // both corners clamped to 0   -> take .x

    const int ia = y0c * ST_W + xa;     // row y0, elements xa, xa+1
    const int ib = y1c * ST_W + xa;     // row y1

    const float* __restrict__ Xb = X + (size_t)b * (ST_C * ST_H * ST_W);
    float* __restrict__ ob = out + (size_t)b * (ST_C * ST_H * ST_W) + pix;

#pragma unroll
    for (int c = 0; c < ST_C; ++c) {
        const float* __restrict__ Xc = Xb + c * (ST_H * ST_W);
        const f2 v0 = ((const f2_a4*)(Xc + ia))->v;   // (Ia, Ic) pre-select
        const f2 v1 = ((const f2_a4*)(Xc + ib))->v;   // (Ib, Id) pre-select
        const float Ia = hi ? v0.y : v0.x;
        const float Ic = lo ? v0.x : v0.y;
        const float Ib = hi ? v1.y : v1.x;
        const float Id = lo ? v1.x : v1.y;
        const float v = wa * Ia + wb * Ib + wc * Ic + wd * Id;
        // nontemporal: output has zero reuse; keep L2/L3 for the gathers
        __builtin_nontemporal_store(v, ob + c * (ST_H * ST_W));
    }
}

extern "C" void kernel_launch(void* const* d_in, const int* in_sizes, int n_in,
                              void* d_out, int out_size, void* d_ws, size_t ws_size,
                              hipStream_t stream) {
    const float* X     = (const float*)d_in[0];
    const float* theta = (const float*)d_in[1];
    float* out         = (float*)d_out;

    const int B = in_sizes[1] / 6;                  // 32
    const int total = B * ST_H * ST_W;
    const int block = 256;
    const int grid = (total + block - 1) / block;   // 32768, divisible by 8
    const int chunk = grid / 8;                     // blocks per XCD

    st_bilinear_kernel<<<grid, block, 0, stream>>>(X, theta, out, B, chunk);
}